// Round 11
// baseline (93.120 us; speedup 1.0000x reference)
//
#include <hip/hip_runtime.h>

// Router: out[t] = x[t] @ W[split[t]] + b[split[t]]
// N=262144, D=128, E=8. fp32 in/out, bf16 MFMA.
// R11: phase-serial block (R3-style, best so far) x 4 blocks/CU x pinned
// 64KB-in-flight prefetch. __launch_bounds__(256,4) + sched_barrier(0) keeps
// xv[16] (64 VGPR) live (R4 failed because the compiler sank these loads:
// VGPR=52). All barriers are lgkmcnt-only so the x loads drain at their
// counted first use (scatter), never at a barrier. 4 staggered blocks/CU
// give ~256KB in flight per CU vs ~64KB in every prior round.

typedef __bf16 bf16x8 __attribute__((ext_vector_type(8)));
typedef float f32x4 __attribute__((ext_vector_type(4)));

__device__ __forceinline__ unsigned short f2bf(float f) {
    unsigned u = __builtin_bit_cast(unsigned, f);
    u += 0x7FFFu + ((u >> 16) & 1u);   // RNE
    return (unsigned short)(u >> 16);
}
__device__ __forceinline__ unsigned pack2(float a, float b) {
    return (unsigned)f2bf(a) | ((unsigned)f2bf(b) << 16);
}

// Transpose + convert W[e][f][g] (f32) -> Wt[e][g][f] (bf16).
__global__ void k_wt(const float* __restrict__ W, unsigned short* __restrict__ Wt) {
    __shared__ float T[16][132];
    int e = blockIdx.x >> 3;
    int g0 = (blockIdx.x & 7) << 4;
    const float* We = W + e * 128 * 128;
    #pragma unroll
    for (int i = 0; i < 2; ++i) {
        int idx = i * 256 + threadIdx.x;
        int f = idx >> 2, q = idx & 3;
        float4 v = *(const float4*)(We + f * 128 + g0 + q * 4);
        T[q * 4 + 0][f] = v.x; T[q * 4 + 1][f] = v.y;
        T[q * 4 + 2][f] = v.z; T[q * 4 + 3][f] = v.w;
    }
    __syncthreads();
    int g = threadIdx.x >> 4, fc = threadIdx.x & 15;
    unsigned short o[8];
    #pragma unroll
    for (int j = 0; j < 8; ++j) o[j] = f2bf(T[g][fc * 8 + j]);
    #pragma unroll
    for (int j = 0; j < 4; ++j)
        ((unsigned*)(Wt + (e * 128 + g0 + g) * 128 + fc * 8))[j] =
            (unsigned)o[2 * j] | ((unsigned)o[2 * j + 1] << 16);
}

#define NT 128

__global__ __launch_bounds__(256, 4) void k_fused(
    const float* __restrict__ x, const int* __restrict__ split,
    const float* __restrict__ bias, const unsigned short* __restrict__ Wt,
    float* __restrict__ out) {

    __shared__ unsigned short A[NT * 128];        // 32 KB bf16, bucketed+swizzled
    __shared__ int wcnt[2][8];
    __shared__ int cntE[8], startE[8];
    __shared__ int dest[NT], trow[NT];

    const int tid = threadIdx.x;
    const int lane = tid & 63, w = tid >> 6;
    const int l15 = lane & 15, lq = lane >> 4;
    const long t0 = (long)blockIdx.x * NT;

    // LDS-visibility barrier that does NOT drain vmcnt (loads stay in flight)
    auto LBAR = [&]() {
        asm volatile("s_waitcnt lgkmcnt(0)" ::: "memory");
        __builtin_amdgcn_s_barrier();
    };

    // ---- ph1: issue the whole 64KB window, pin the issue point ----
    float4 xv[16];
    const float* xb = x + t0 * 128;
    #pragma unroll
    for (int rr = 0; rr < 16; ++rr)
        xv[rr] = *(const float4*)(xb + (rr * 256 + tid) * 4);
    __builtin_amdgcn_sched_barrier(0);

    // ---- ph2: ballot bucketing (token waves are w=0,1) ----
    int e = 255, rank = 0;
    if (tid < NT) e = split[t0 + tid];
    const unsigned long long below = (1ull << lane) - 1;
    #pragma unroll
    for (int ee = 0; ee < 8; ++ee) {
        unsigned long long m = __ballot(e == ee);
        if (e == ee) rank = (int)__popcll(m & below);
        if (w < 2 && lane == ee) wcnt[w][ee] = (int)__popcll(m);
    }
    LBAR();

    if (tid < NT) {
        int s = 0;
        #pragma unroll
        for (int ee = 0; ee < 8; ++ee) s += (ee < e) ? (wcnt[0][ee] + wcnt[1][ee]) : 0;
        int slot = s + (w == 1 ? wcnt[0][e] : 0) + rank;   // bijective over [0,NT)
        dest[tid] = slot;
        trow[slot] = tid;
    }
    if (tid < 8) {
        int s = 0;
        #pragma unroll
        for (int ee = 0; ee < 8; ++ee) s += (ee < tid) ? (wcnt[0][ee] + wcnt[1][ee]) : 0;
        startE[tid] = s;
        cntE[tid] = wcnt[0][tid] + wcnt[1][tid];
    }
    LBAR();

    // ---- ph3: cvt f32->bf16, scatter into bucketed+swizzled A ----
    // (first use of xv -> compiler emits counted vmcnt waits here)
    #pragma unroll
    for (int rr = 0; rr < 16; ++rr) {
        int c = rr * 256 + tid;          // 16B f32 chunk id (4096 total)
        int row = c >> 5;
        int s = dest[row];
        int fc = (c & 31) >> 1, half = c & 1;
        *(uint2*)(&A[s * 128 + ((fc ^ (s & 7)) << 3) + half * 4]) =
            make_uint2(pack2(xv[rr].x, xv[rr].y), pack2(xv[rr].z, xv[rr].w));
    }
    LBAR();

    // ---- ph4: compute; wave w owns cols [w*32, w*32+32) ----
    #pragma unroll
    for (int ee = 0; ee < 8; ++ee) {
        int cnt = cntE[ee];
        if (cnt == 0) continue;
        int st = startE[ee];

        bf16x8 bfrag0[4], bfrag1[4];
        #pragma unroll
        for (int kk = 0; kk < 4; ++kk) {
            bfrag0[kk] = *(const bf16x8*)(Wt + (ee * 128 + w * 32 + l15) * 128 + kk * 32 + lq * 8);
            bfrag1[kk] = *(const bf16x8*)(Wt + (ee * 128 + w * 32 + 16 + l15) * 128 + kk * 32 + lq * 8);
        }
        float bv0 = bias[ee * 128 + w * 32 + l15];
        float bv1 = bias[ee * 128 + w * 32 + 16 + l15];

        for (int rb = st; rb < st + cnt; rb += 16) {
            int lim = st + cnt - rb; lim = lim < 16 ? lim : 16;
            int sr = rb + l15; sr = sr < NT ? sr : NT - 1;   // A is in slot order
            f32x4 acc0 = {0.f, 0.f, 0.f, 0.f}, acc1 = {0.f, 0.f, 0.f, 0.f};
            #pragma unroll
            for (int kk = 0; kk < 4; ++kk) {
                int fc = kk * 4 + lq;
                bf16x8 a = *(const bf16x8*)(&A[sr * 128 + ((fc ^ (sr & 7)) << 3)]);
                acc0 = __builtin_amdgcn_mfma_f32_16x16x32_bf16(a, bfrag0[kk], acc0, 0, 0, 0);
                acc1 = __builtin_amdgcn_mfma_f32_16x16x32_bf16(a, bfrag1[kk], acc1, 0, 0, 0);
            }
            #pragma unroll
            for (int r = 0; r < 4; ++r) {
                int ri = lq * 4 + r;
                if (ri < lim) {
                    int tok = trow[rb + ri];              // slot -> token (store only)
                    float* o = out + (t0 + tok) * 128 + w * 32 + l15;
                    o[0]  = acc0[r] + bv0;
                    o[16] = acc1[r] + bv1;
                }
            }
        }
    }
}

extern "C" void kernel_launch(void* const* d_in, const int* in_sizes, int n_in,
                              void* d_out, int out_size, void* d_ws, size_t ws_size,
                              hipStream_t stream) {
    const float* x     = (const float*)d_in[0];
    const int*   split = (const int*)d_in[1];
    const float* W     = (const float*)d_in[2];
    const float* bias  = (const float*)d_in[3];
    float* out = (float*)d_out;

    int n = in_sizes[1];                      // 262144
    unsigned short* Wt = (unsigned short*)d_ws;   // 8*128*128 bf16 = 256 KB

    k_wt<<<64, 256, 0, stream>>>(W, Wt);
    k_fused<<<n / NT, 256, 0, stream>>>(x, split, bias, Wt, out);
}